// Round 3
// baseline (540.088 us; speedup 1.0000x reference)
//
#include <hip/hip_runtime.h>
#include <hip/hip_cooperative_groups.h>
#include <stdint.h>

namespace cg = cooperative_groups;

#define QMAXF 127.0f

constexpr int Mdim = 8192;
constexpr int Kdim = 4096;
constexpr int Ndim = 4096;
constexpr int PREP_BLOCKS = 1024;  // 4 blocks/CU -> co-residency guaranteed

using i32x4 = __attribute__((ext_vector_type(4))) int;

__device__ __forceinline__ void async_copy16(const void* g, void* l) {
    __builtin_amdgcn_global_load_lds(
        (const __attribute__((address_space(1))) void*)g,
        (__attribute__((address_space(3))) void*)l,
        16, 0, 0);
}

// ---------------------------------------------------------------------------
// ONE cooperative prep kernel:
//   A: per-block |x| max (no atomics) + w int32->int8 narrowing
//   grid.sync()
//   B: every block redundantly reduces the 1024 block maxima (4KB, L2-hot)
//   C: quantize x -> int8 (x re-read is L3-resident: 134MB < 256MB LLC)
// ---------------------------------------------------------------------------
__global__ __launch_bounds__(256) void prep_coop_kernel(
    const float* __restrict__ x, const int* __restrict__ w32,
    float* __restrict__ blockmax, int8_t* __restrict__ w8,
    int8_t* __restrict__ xq, float* __restrict__ sxp) {
    const int n4x = Mdim * Kdim / 4;
    const int n4w = Ndim * Kdim / 4;
    const int gstride = PREP_BLOCKS * 256;
    const int gtid = blockIdx.x * 256 + threadIdx.x;

    // ---- phase A: absmax over x ----
    float m = 0.f;
    const float4* x4 = (const float4*)x;
    for (int i = gtid; i < n4x; i += gstride) {
        float4 v = x4[i];
        m = fmaxf(fmaxf(fabsf(v.x), fabsf(v.y)),
                  fmaxf(m, fmaxf(fabsf(v.z), fabsf(v.w))));
    }
#pragma unroll
    for (int off = 32; off > 0; off >>= 1)
        m = fmaxf(m, __shfl_down(m, off, 64));
    __shared__ float red[4];
    if ((threadIdx.x & 63) == 0) red[threadIdx.x >> 6] = m;
    __syncthreads();
    if (threadIdx.x == 0)
        blockmax[blockIdx.x] =
            fmaxf(fmaxf(red[0], red[1]), fmaxf(red[2], red[3]));

    // ---- phase A': narrow w (independent work, overlaps the store above) ----
    const int4* in4 = (const int4*)w32;
    char4* out4 = (char4*)w8;
    for (int i = gtid; i < n4w; i += gstride) {
        int4 v = in4[i];
        char4 c;
        c.x = (signed char)v.x;
        c.y = (signed char)v.y;
        c.z = (signed char)v.z;
        c.w = (signed char)v.w;
        out4[i] = c;
    }

    cg::this_grid().sync();

    // ---- phase B: all blocks redundantly reduce 1024 maxima ----
    float gm = 0.f;
    for (int i = threadIdx.x; i < PREP_BLOCKS; i += 256)
        gm = fmaxf(gm, blockmax[i]);
#pragma unroll
    for (int off = 32; off > 0; off >>= 1)
        gm = fmaxf(gm, __shfl_down(gm, off, 64));
    __shared__ float red2[4];
    if ((threadIdx.x & 63) == 0) red2[threadIdx.x >> 6] = gm;
    __syncthreads();
    __shared__ float s_sh;
    if (threadIdx.x == 0) {
        const float s =
            fmaxf(fmaxf(red2[0], red2[1]), fmaxf(red2[2], red2[3])) / QMAXF;
        s_sh = s;
        if (blockIdx.x == 0) *sxp = s;  // for the GEMM epilogue
    }
    __syncthreads();
    const float s = s_sh;

    // ---- phase C: quantize x ----
    char4* q4 = (char4*)xq;
    for (int i = gtid; i < n4x; i += gstride) {
        float4 v = x4[i];
        char4 q;
        q.x = (signed char)(int)fminf(QMAXF, fmaxf(-QMAXF, rintf(v.x / s)));
        q.y = (signed char)(int)fminf(QMAXF, fmaxf(-QMAXF, rintf(v.y / s)));
        q.z = (signed char)(int)fminf(QMAXF, fmaxf(-QMAXF, rintf(v.z / s)));
        q.w = (signed char)(int)fminf(QMAXF, fmaxf(-QMAXF, rintf(v.w / s)));
        q4[i] = q;
    }
}

// ---------------------------------------------------------------------------
// int8 GEMM: C[M,N] = Xq[M,K] . Wq[N,K]^T   (unchanged from R2: 128x128 tile,
// BK=128B, XOR-swizzled LDS -> 0 bank conflicts, global_load_lds width=16)
// ---------------------------------------------------------------------------
#define BM 128
#define BN 128
#define BK 128

__global__ __launch_bounds__(256) void gemm_i8_kernel(
    const int8_t* __restrict__ Xq, const int8_t* __restrict__ Wq,
    const float* __restrict__ sxp, const float* __restrict__ s_w,
    const float* __restrict__ bias, float* __restrict__ Y) {
    __shared__ int8_t As[BM * BK];
    __shared__ int8_t Bs[BN * BK];

    const int t = threadIdx.x;
    const int w = t >> 6;
    const int l = t & 63;
    const int lane15 = l & 15;
    const int lquad = l >> 4;
    const int swz = lane15 & 7;
    const int wm = (w >> 1) * 64;
    const int wn = (w & 1) * 64;

    const int bm = blockIdx.y * BM;
    const int bn = blockIdx.x * BN;

    const int8_t* aptr[4];
    const int8_t* bptr[4];
#pragma unroll
    for (int s = 0; s < 4; s++) {
        const int cl = t + 256 * s;
        const int r = cl >> 3;
        const int c = ((cl & 7) ^ (r & 7)) * 16;
        aptr[s] = Xq + (size_t)(bm + r) * Kdim + c;
        bptr[s] = Wq + (size_t)(bn + r) * Kdim + c;
    }
    int8_t* alds[4];
    int8_t* blds[4];
#pragma unroll
    for (int s = 0; s < 4; s++) {
        alds[s] = As + s * 4096 + w * 1024;
        blds[s] = Bs + s * 4096 + w * 1024;
    }

    i32x4 acc[4][4] = {};

    for (int kt = 0; kt < Kdim; kt += BK) {
#pragma unroll
        for (int s = 0; s < 4; s++) async_copy16(aptr[s] + kt, alds[s]);
#pragma unroll
        for (int s = 0; s < 4; s++) async_copy16(bptr[s] + kt, blds[s]);
        __syncthreads();

#pragma unroll
        for (int kk = 0; kk < 2; kk++) {
            i32x4 a[4], b[4];
#pragma unroll
            for (int i = 0; i < 4; i++)
                a[i] = *(const i32x4*)(As + (wm + i * 16 + lane15) * BK +
                                       (((kk << 2) | lquad) ^ swz) * 16);
#pragma unroll
            for (int j = 0; j < 4; j++)
                b[j] = *(const i32x4*)(Bs + (wn + j * 16 + lane15) * BK +
                                       (((kk << 2) | lquad) ^ swz) * 16);
#pragma unroll
            for (int i = 0; i < 4; i++)
#pragma unroll
                for (int j = 0; j < 4; j++)
                    acc[i][j] = __builtin_amdgcn_mfma_i32_16x16x64_i8(
                        a[i], b[j], acc[i][j], 0, 0, 0);
        }
        __syncthreads();
    }

    const float sx = *sxp;
#pragma unroll
    for (int j = 0; j < 4; j++) {
        const int col = bn + wn + j * 16 + lane15;
        const float sc = sx * s_w[col];
        const float bs = bias[col];
#pragma unroll
        for (int i = 0; i < 4; i++) {
            const int row = bm + wm + i * 16 + lquad * 4;
            float* yp = Y + (size_t)row * Ndim + col;
#pragma unroll
            for (int r = 0; r < 4; r++)
                yp[(size_t)r * Ndim] = (float)acc[i][j][r] * sc + bs;
        }
    }
}

extern "C" void kernel_launch(void* const* d_in, const int* in_sizes, int n_in,
                              void* d_out, int out_size, void* d_ws,
                              size_t ws_size, hipStream_t stream) {
    const float* x = (const float*)d_in[0];
    const int* w_q = (const int*)d_in[1];  // integer inputs arrive as int32
    const float* s_w = (const float*)d_in[2];
    const float* bias = (const float*)d_in[3];
    float* y = (float*)d_out;

    float* sx = (float*)d_ws;                       // scalar scale
    float* blockmax = (float*)((char*)d_ws + 256);  // 1024 floats
    int8_t* xq = (int8_t*)d_ws + 16384;
    int8_t* wq8 = (int8_t*)d_ws + 16384 + (size_t)Mdim * Kdim;

    void* args[] = {(void*)&x,   (void*)&w_q, (void*)&blockmax,
                    (void*)&wq8, (void*)&xq,  (void*)&sx};
    hipLaunchCooperativeKernel((const void*)prep_coop_kernel,
                               dim3(PREP_BLOCKS), dim3(256), args, 0, stream);

    dim3 grid(Ndim / BN, Mdim / BM);
    gemm_i8_kernel<<<grid, 256, 0, stream>>>(xq, wq8, sx, s_w, bias, y);
}